// Round 10
// baseline (173.272 us; speedup 1.0000x reference)
//
#include <hip/hip_runtime.h>
#include <math.h>

#define T_LEN 4096
#define D_IN 128
#define KDIM 4096   // TR*CTX
#define K2   8192   // re+im
#define NBLK 256

// ws float offsets
#define OFF_GATED 0u
#define OFF_GO    262144u
#define OFF_SKIP  524288u
#define OFF_PART  786432u          // 16 * 262144 partials
#define OFF_FLAGS 4980736u         // 4096 ints
#define OFF_CHS   4984832u         // 64 ints
#define OFF_WZT   4984896u         // 524288 bf16 = 262144 float slots
#define OFF_SCR   5247040u         // carryB 524288 + cinArr 524288 floats
#define OFF_BAR   6295616u         // barrier ints (64)

typedef __attribute__((ext_vector_type(8))) short short8v;
typedef __attribute__((ext_vector_type(4))) float float4v;

__device__ __forceinline__ float sigm(float x){ return 1.f/(1.f+expf(-x)); }
__device__ __forceinline__ unsigned short f2bf(float x){
    unsigned int u = __float_as_uint(x);
    return (unsigned short)((u + 0x7FFFu + ((u >> 16) & 1u)) >> 16);
}
__device__ __forceinline__ float wsum(float v) {
#pragma unroll
    for (int o = 32; o; o >>= 1) v += __shfl_xor(v, o, 64);
    return v;
}

struct Params {
    const unsigned char* su8; const int* si32;
    const float *x, *st0, *a, *b;
    const float *W1,*b1,*W2,*b2,*Wgi,*bgi,*Wp,*bp,*Wz,*bz,*Wgo,*bgo,*Wsk,*bsk,*W3,*b3,*W4,*b4;
    float *gated,*go,*sk,*part; int *flags,*chs; unsigned short* wzt;
    float2 *carryB,*cinArr; float* out; int* bar;
};

// grid barrier: all 256 blocks guaranteed co-resident (<=1 CU of resources each).
__device__ __forceinline__ void gsync(int* bar) {
    __syncthreads();
    if (threadIdx.x == 0) {
        __threadfence();                 // release: flush my block's writes
        atomicAdd(bar, 1);
        while (atomicAdd(bar, 0) < NBLK) __builtin_amdgcn_s_sleep(8);
        __threadfence();                 // acquire: invalidate L1/L2 for fresh reads
    }
    __syncthreads();
}

__global__ __launch_bounds__(512) void k_mega(Params P) {
    __shared__ __align__(16) char smem[65536];
    const int bx = blockIdx.x;
    const int tid = threadIdx.x;

    // ================= P0: flags | wzt | mlp =================
    if (bx == 0) {
        int* cnt = (int*)(smem + 20480);
        if (tid == 0) *cnt = 0;
        __syncthreads();
        int local = 0;
        for (int i = tid; i < 4096; i += 512)
            if (i & 3) local += P.su8[i];
        if (local) atomicAdd(cnt, local);
        __syncthreads();
        if (*cnt > 0) { for (int i = tid; i < 4096; i += 512) P.flags[i] = P.su8[i] ? 1 : 0; }
        else          { for (int i = tid; i < 4096; i += 512) P.flags[i] = P.si32[i] ? 1 : 0; }
        __syncthreads();
        if (tid < 64) {
            int any = 0;
#pragma unroll 8
            for (int j = 0; j < 64; ++j) any |= P.flags[tid * 64 + j];
            P.chs[tid] = any;
        }
    }
    if (bx >= 1 && bx <= 64) {   // wzt[j][k] = bf16(Wz[k][j])
        int idx = ((bx - 1) * 512 + tid) * 16;
        int j = idx >> 13, k0 = idx & 8191;
#pragma unroll
        for (int e = 0; e < 16; ++e) {
            int k = k0 + e;
            P.wzt[(size_t)j * K2 + k] = f2bf(P.Wz[(size_t)k * 64 + j]);
        }
    }
    {   // mlp: 2 units of 8 rows per block, weights hoisted in VGPRs
        float (*xs)[128]  = (float(*)[128])smem;
        float (*hs)[64]   = (float(*)[64])(smem + 4096);
        float (*h2s)[128] = (float(*)[128])(smem + 6144);
        float (*tmp)[4][64] = (float(*)[4][64])(smem + 10240);

        const int j1 = tid >> 3, ks1 = tid & 7;
        float wr1[16];
#pragma unroll
        for (int kk = 0; kk < 16; ++kk) wr1[kk] = P.W1[(size_t)(ks1 * 16 + kk) * 64 + j1];
        const float bias1 = P.b1[j1];
        const int j2 = tid >> 2, ks2 = tid & 3;
        float wr2[16];
#pragma unroll
        for (int kk = 0; kk < 16; ++kk) wr2[kk] = P.W2[(size_t)(ks2 * 16 + kk) * 128 + j2];
        const float bias2 = P.b2[j2];
        const int mat = tid >> 7, jj = (tid & 127) >> 1, kh = tid & 1;
        const float* Wm = (mat == 0) ? P.Wgi : (mat == 1) ? P.Wp : (mat == 2) ? P.Wgo : P.Wsk;
        float wgr[64];
#pragma unroll
        for (int kk = 0; kk < 64; ++kk) wgr[kk] = Wm[(size_t)(kh * 64 + kk) * 64 + jj];

        for (int u = 0; u < 2; ++u) {
            const int t0 = (bx * 2 + u) * 8;
            __syncthreads();
            if (tid < 256) {
                int r = tid >> 5, kq = (tid & 31) << 2;
                *(float4*)&xs[r][kq] = *(const float4*)&P.x[(size_t)(t0 + r) * D_IN + kq];
            }
            __syncthreads();
#pragma unroll
            for (int r = 0; r < 8; ++r) {
                float p = 0.f;
#pragma unroll
                for (int kq = 0; kq < 4; ++kq) {
                    float4 xv = *(const float4*)&xs[r][ks1 * 16 + kq * 4];
                    p += xv.x*wr1[kq*4] + xv.y*wr1[kq*4+1] + xv.z*wr1[kq*4+2] + xv.w*wr1[kq*4+3];
                }
                p += __shfl_xor(p, 1, 64); p += __shfl_xor(p, 2, 64); p += __shfl_xor(p, 4, 64);
                if (ks1 == 0) hs[r][j1] = fmaxf(p + bias1, 0.f);
            }
            __syncthreads();
#pragma unroll
            for (int r = 0; r < 8; ++r) {
                float p = 0.f;
#pragma unroll
                for (int kq = 0; kq < 4; ++kq) {
                    float4 hv = *(const float4*)&hs[r][ks2 * 16 + kq * 4];
                    p += hv.x*wr2[kq*4] + hv.y*wr2[kq*4+1] + hv.z*wr2[kq*4+2] + hv.w*wr2[kq*4+3];
                }
                p += __shfl_xor(p, 1, 64); p += __shfl_xor(p, 2, 64);
                if (ks2 == 0) h2s[r][j2] = p + bias2;
            }
            __syncthreads();
#pragma unroll
            for (int r = 0; r < 8; ++r) {
                float p = 0.f;
#pragma unroll
                for (int kq = 0; kq < 16; ++kq) {
                    float4 hv = *(const float4*)&h2s[r][kh * 64 + kq * 4];
                    p += hv.x*wgr[kq*4] + hv.y*wgr[kq*4+1] + hv.z*wgr[kq*4+2] + hv.w*wgr[kq*4+3];
                }
                p += __shfl_xor(p, 1, 64);
                if (kh == 0) tmp[r][mat][jj] = p;
            }
            __syncthreads();
            {
                int r = tid >> 6, j = tid & 63;
                int t = t0 + r;
                float gi = sigm(tmp[r][0][j] + P.bgi[j]);
                float pr = sigm(tmp[r][1][j] + P.bp[j]);
                float g  = sigm(tmp[r][2][j] + P.bgo[j]);
                float s  = tmp[r][3][j] + P.bsk[j];
                P.gated[t * 64 + j] = gi * pr;
                P.go[t * 64 + j]    = g;
                P.sk[t * 64 + j]    = s;
            }
        }
    }
    gsync(P.bar + 0);

    // ================= P1: scanA (per-chunk local carries) =================
    {
        const int p = tid >> 6, c = tid & 63;
#pragma unroll
        for (int u = 0; u < 2; ++u) {
            const int pair = (bx * 2 + u) * 8 + p;
            const int ch = pair & 63, m = pair >> 6, t0s = ch * 64;
            const double ea = exp(-fabs((double)P.a[m]));
            const double bb = (double)P.b[c];
            const double lre = ea * cos(bb), lim = ea * sin(bb);
            float gv = P.gated[(size_t)(t0s + c) * 64 + m];
            unsigned long long fmask = __ballot(P.flags[t0s + c] != 0);
            double sre = 0.0, sim = 0.0;
#pragma unroll 8
            for (int j = 0; j < 64; ++j) {
                double g = (double)__shfl(gv, j, 64);
                if ((fmask >> j) & 1) { sre = g; sim = 0.0; }
                else {
                    double nr = fma(sre, lre, fma(-sim, lim, g));
                    double ni = fma(sre, lim, sim * lre);
                    sre = nr; sim = ni;
                }
            }
            P.carryB[(size_t)ch * KDIM + m * 64 + c] = make_float2((float)sre, (float)sim);
        }
    }
    gsync(P.bar + 16);

    // ================= P2: scanC (carry scan over chunks) =================
    if (bx < 64 && tid < 64) {
        const int m = bx, c = tid;
        unsigned long long cmask = __ballot(P.chs[c] != 0);
        float2 Bv[64];
#pragma unroll
        for (int ch = 0; ch < 64; ++ch)
            Bv[ch] = P.carryB[(size_t)ch * KDIM + m * 64 + c];
        const double ea64 = exp(-64.0 * fabs((double)P.a[m]));
        const double bb = (double)P.b[c];
        const double l64re = ea64 * cos(64.0 * bb), l64im = ea64 * sin(64.0 * bb);
        double cre = (double)P.st0[(m * 64 + c) * 2];
        double cim = (double)P.st0[(m * 64 + c) * 2 + 1];
#pragma unroll
        for (int ch = 0; ch < 64; ++ch) {
            P.cinArr[(size_t)ch * KDIM + m * 64 + c] = make_float2((float)cre, (float)cim);
            if ((cmask >> ch) & 1) { cre = (double)Bv[ch].x; cim = (double)Bv[ch].y; }
            else {
                double nr = fma(cre, l64re, fma(-cim, l64im, (double)Bv[ch].x));
                double ni = fma(cre, l64im, fma(cim, l64re, (double)Bv[ch].y));
                cre = nr; cim = ni;
            }
        }
    }
    gsync(P.bar + 32);

    // ================= P3: scanBZ (seeded scan -> LDS tile -> MFMA) =================
    {
        unsigned short* st = (unsigned short*)smem;
        const int w = tid >> 6, l = tid & 63;
        const int ml = w & 3, mth = w >> 2;
        for (int u = 0; u < 4; ++u) {
            const int pair = bx * 4 + u;
            const int ch = pair & 63, mg = pair >> 6, t0s = ch * 64;
            const int m = mg * 4 + ml;
            const int jrow = ml * 16 + (l & 15);
            short8v bfr[16];
#pragma unroll
            for (int ks = 0; ks < 16; ++ks)
                bfr[ks] = *(const short8v*)&P.wzt[(size_t)jrow * K2 + mg * 512 + (ks * 4 + (l >> 4)) * 8];
            __syncthreads();   // previous iteration's MFMA reads finished before overwriting st
            if (w < 4) {
                const double ea = exp(-fabs((double)P.a[m]));
                const double bb = (double)P.b[l];
                const double lre = ea * cos(bb), lim = ea * sin(bb);
                float gv = P.gated[(size_t)(t0s + l) * 64 + m];
                unsigned long long fmask = __ballot(P.flags[t0s + l] != 0);
                float2 cin = P.cinArr[(size_t)ch * KDIM + m * 64 + l];
                double sre = (double)cin.x, sim = (double)cin.y;
                const int e0 = ml * 128 + l, e1 = e0 + 64;
#pragma unroll 4
                for (int j = 0; j < 64; ++j) {
                    double g = (double)__shfl(gv, j, 64);
                    if ((fmask >> j) & 1) { sre = g; sim = 0.0; }
                    else {
                        double nr = fma(sre, lre, fma(-sim, lim, g));
                        double ni = fma(sre, lim, sim * lre);
                        sre = nr; sim = ni;
                    }
                    const int sx = (j & 7) << 3;
                    st[j * 512 + (e0 ^ sx)] = f2bf((float)sre);
                    st[j * 512 + (e1 ^ sx)] = f2bf((float)sim);
                }
                if (ch == 63) {
                    P.out[524288 + m * 64 + l]        = (float)sre;
                    P.out[524288 + 4096 + m * 64 + l] = (float)sim;
                }
            }
            __syncthreads();
            float4v acc[2];
            acc[0] = (float4v){0.f,0.f,0.f,0.f};
            acc[1] = (float4v){0.f,0.f,0.f,0.f};
#pragma unroll
            for (int ks = 0; ks < 16; ++ks) {
#pragma unroll
                for (int q = 0; q < 2; ++q) {
                    const int row = (mth * 2 + q) * 16 + (l & 15);
                    const int rchunk = (ks * 4 + (l >> 4)) ^ (row & 7);
                    short8v af = *(const short8v*)&st[row * 512 + rchunk * 8];
                    acc[q] = __builtin_amdgcn_mfma_f32_16x16x32_bf16(af, bfr[ks], acc[q], 0, 0, 0);
                }
            }
            float* pp = P.part + (size_t)mg * 262144;
            const int jcol = ml * 16 + (l & 15);
#pragma unroll
            for (int q = 0; q < 2; ++q) {
                const int trow = t0s + (mth * 2 + q) * 16 + (l >> 4) * 4;
#pragma unroll
                for (int r = 0; r < 4; ++r)
                    pp[(size_t)(trow + r) * 64 + jcol] = acc[q][r];
            }
        }
    }
    gsync(P.bar + 48);

    // ================= P4: epilogue (16 rows/block, wave-private LDS) =================
    {
        float (*ob)[64] = (float(*)[64])smem;
        float (*hb)[64] = (float(*)[64])(smem + 2048);
        const int w = tid >> 6, j = tid & 63;
        for (int it = 0; it < 2; ++it) {
            const int t = bx * 16 + it * 8 + w;
            float z = P.bz[j];
#pragma unroll
            for (int p = 0; p < 16; ++p) z += P.part[(size_t)p * 262144 + t * 64 + j];
            float g = P.go[t * 64 + j];
            float y = z * g;
            float mu = wsum(y) * 0.015625f;
            float d = y - mu;
            float var = wsum(d * d) * 0.015625f;
            float o = d * (1.f / sqrtf(var + 1e-6f)) + P.sk[t * 64 + j] * (1.f - g);
            ob[w][j] = o;
            float acc2 = P.b3[j];
#pragma unroll 8
            for (int k = 0; k < 64; ++k) acc2 += ob[w][k] * P.W3[k * 64 + j];
            hb[w][j] = fmaxf(acc2, 0.f);
            float o1 = P.b4[j], o2 = P.b4[j + 64];
#pragma unroll 8
            for (int k = 0; k < 64; ++k) { float hv = hb[w][k]; o1 += hv * P.W4[k * 128 + j]; o2 += hv * P.W4[k * 128 + j + 64]; }
            P.out[(size_t)t * 128 + j] = o1;
            P.out[(size_t)t * 128 + j + 64] = o2;
        }
    }
}

// ----------------------------------------------------------------
extern "C" void kernel_launch(void* const* d_in, const int* in_sizes, int n_in,
                              void* d_out, int out_size, void* d_ws, size_t ws_size,
                              hipStream_t stream)
{
    float* ws = (float*)d_ws;
    Params P;
    P.su8 = (const unsigned char*)d_in[2];
    P.si32 = (const int*)d_in[2];
    P.x   = (const float*)d_in[0];
    P.st0 = (const float*)d_in[1];
    P.a   = (const float*)d_in[3];
    P.b   = (const float*)d_in[4];
    P.W1  = (const float*)d_in[5];  P.b1  = (const float*)d_in[6];
    P.W2  = (const float*)d_in[7];  P.b2  = (const float*)d_in[8];
    P.Wgi = (const float*)d_in[9];  P.bgi = (const float*)d_in[10];
    P.Wp  = (const float*)d_in[11]; P.bp  = (const float*)d_in[12];
    P.Wz  = (const float*)d_in[13]; P.bz  = (const float*)d_in[14];
    P.Wgo = (const float*)d_in[15]; P.bgo = (const float*)d_in[16];
    P.Wsk = (const float*)d_in[17]; P.bsk = (const float*)d_in[18];
    P.W3  = (const float*)d_in[19]; P.b3  = (const float*)d_in[20];
    P.W4  = (const float*)d_in[21]; P.b4  = (const float*)d_in[22];
    P.gated = ws + OFF_GATED;
    P.go    = ws + OFF_GO;
    P.sk    = ws + OFF_SKIP;
    P.part  = ws + OFF_PART;
    P.flags = (int*)(ws + OFF_FLAGS);
    P.chs   = (int*)(ws + OFF_CHS);
    P.wzt   = (unsigned short*)(ws + OFF_WZT);
    P.carryB = (float2*)(ws + OFF_SCR);
    P.cinArr = (float2*)(ws + OFF_SCR + 524288);
    P.out   = (float*)d_out;
    P.bar   = (int*)(ws + OFF_BAR);

    hipMemsetAsync(P.bar, 0, 64 * sizeof(int), stream);
    hipLaunchKernelGGL(k_mega, dim3(NBLK), dim3(512), 0, stream, P);
}